// Round 1
// baseline (316.541 us; speedup 1.0000x reference)
//
#include <hip/hip_runtime.h>
#include <stdint.h>

#define B_ROWS 4096
#define N_ROWS 8192
#define D_DIM  1024
#define BK     64

typedef __attribute__((ext_vector_type(8))) short bf16x8;
typedef __attribute__((ext_vector_type(4))) float f32x4;

// round-to-nearest-even f32 -> bf16
static __device__ __forceinline__ unsigned short f2bf(float f) {
  uint32_t u = __float_as_uint(f);
  u += 0x7fff + ((u >> 16) & 1);
  return (unsigned short)(u >> 16);
}

static __device__ __forceinline__ void async_copy16(const unsigned short* g, unsigned short* l) {
  __builtin_amdgcn_global_load_lds(
      (const __attribute__((address_space(1))) unsigned int*)g,
      (__attribute__((address_space(3))) unsigned int*)l, 16, 0, 0);
}

// One block per row: L2-normalize, cast to bf16, and zero rowsum.
__global__ __launch_bounds__(256) void normalize_kernel(
    const float* __restrict__ f1, const float* __restrict__ f2,
    unsigned short* __restrict__ F, float* __restrict__ rowsum) {
  const int row = blockIdx.x;
  const int tid = threadIdx.x;
  const float* src = (row < B_ROWS) ? (f1 + (size_t)row * D_DIM)
                                    : (f2 + (size_t)(row - B_ROWS) * D_DIM);
  float4 v = ((const float4*)src)[tid];
  float ss = v.x * v.x + v.y * v.y + v.z * v.z + v.w * v.w;
#pragma unroll
  for (int m = 1; m < 64; m <<= 1) ss += __shfl_xor(ss, m, 64);
  __shared__ float red[4];
  if ((tid & 63) == 0) red[tid >> 6] = ss;
  __syncthreads();
  ss = red[0] + red[1] + red[2] + red[3];
  const float invn = 1.0f / fmaxf(sqrtf(ss), 1e-12f);
  ushort4 o;
  o.x = f2bf(v.x * invn); o.y = f2bf(v.y * invn);
  o.z = f2bf(v.z * invn); o.w = f2bf(v.w * invn);
  ((ushort4*)(F + (size_t)row * D_DIM))[tid] = o;
  if (tid == 0) rowsum[row] = 0.0f;
}

// Fused Gram-GEMM + exp-sum epilogue. 128x128 tile / block, 4 waves,
// each wave 64x64 via 4x4 grid of 16x16x32 bf16 MFMA.
__global__ __launch_bounds__(256) void simloss_kernel(
    const unsigned short* __restrict__ F, float* __restrict__ rowsum,
    float* __restrict__ pos) {
  __shared__ unsigned short lA[128 * BK];
  __shared__ unsigned short lB[128 * BK];

  const int tid  = threadIdx.x;
  const int lane = tid & 63;
  const int wv   = __builtin_amdgcn_readfirstlane(tid >> 6);
  const int waveRow = wv >> 1;
  const int waveCol = wv & 1;
  const int q   = lane >> 4;   // quad within wave
  const int l16 = lane & 15;

  const int iBase = blockIdx.y * 128;
  const int jBase = blockIdx.x * 128;

  f32x4 acc[4][4];
#pragma unroll
  for (int a = 0; a < 4; ++a)
#pragma unroll
    for (int b = 0; b < 4; ++b) acc[a][b] = (f32x4){0.f, 0.f, 0.f, 0.f};

  for (int k0 = 0; k0 < D_DIM; k0 += BK) {
    // ---- stage A (rows i) and B (rows j) tiles, XOR-swizzled chunks ----
    // LDS chunk lc (16B) holds global [row = lc>>3][col8 = (lc&7) ^ (row&7)]
#pragma unroll
    for (int it = 0; it < 4; ++it) {
      const int lc   = it * 256 + wv * 64 + lane;
      const int row  = lc >> 3;
      const int gcol = (lc & 7) ^ (row & 7);
      const size_t goff = (size_t)row * D_DIM + k0 + gcol * 8;
      async_copy16(F + (size_t)iBase * D_DIM + goff, lA + lc * 8);
      async_copy16(F + (size_t)jBase * D_DIM + goff, lB + lc * 8);
    }
    __syncthreads();  // compiler emits vmcnt(0) drain before barrier

    // ---- compute: 2 k-substeps of 32 ----
#pragma unroll
    for (int kk = 0; kk < BK; kk += 32) {
      bf16x8 af[4], bfr[4];
      const int cbase = (kk >> 3) + q;
#pragma unroll
      for (int mi = 0; mi < 4; ++mi) {
        const int r  = waveRow * 64 + mi * 16 + l16;
        const int ch = r * 8 + (cbase ^ (r & 7));
        af[mi] = *(const bf16x8*)(lA + ch * 8);
      }
#pragma unroll
      for (int ni = 0; ni < 4; ++ni) {
        const int r  = waveCol * 64 + ni * 16 + l16;
        const int ch = r * 8 + (cbase ^ (r & 7));
        bfr[ni] = *(const bf16x8*)(lB + ch * 8);
      }
#pragma unroll
      for (int mi = 0; mi < 4; ++mi)
#pragma unroll
        for (int ni = 0; ni < 4; ++ni)
          acc[mi][ni] = __builtin_amdgcn_mfma_f32_16x16x32_bf16(
              af[mi], bfr[ni], acc[mi][ni], 0, 0, 0);
    }
    __syncthreads();
  }

  // ---- epilogue: sim = 10*dot; e = exp(sim-10) excluding diagonal;
  //      row-reduce across the 16 lanes sharing a row; pos via unique store.
#pragma unroll
  for (int mi = 0; mi < 4; ++mi) {
#pragma unroll
    for (int reg = 0; reg < 4; ++reg) {
      const int i = iBase + waveRow * 64 + mi * 16 + q * 4 + reg;
      const int jpos = (i + B_ROWS) & (N_ROWS - 1);
      float s = 0.0f;
#pragma unroll
      for (int ni = 0; ni < 4; ++ni) {
        const int j = jBase + waveCol * 64 + ni * 16 + l16;
        const float sim = acc[mi][ni][reg] * 10.0f;
        s += (j == i) ? 0.0f : __expf(sim - 10.0f);
        if (j == jpos) pos[i] = sim;
      }
#pragma unroll
      for (int m = 1; m < 16; m <<= 1) s += __shfl_xor(s, m, 64);
      if (l16 == 0) atomicAdd(&rowsum[i], s);
    }
  }
}

__global__ __launch_bounds__(256) void finalize_kernel(
    const float* __restrict__ rowsum, const float* __restrict__ pos,
    float* __restrict__ out) {
  const int tid = threadIdx.x;
  float a = 0.0f;
  for (int i = tid; i < N_ROWS; i += 256)
    a += logf(rowsum[i]) + 10.0f - pos[i];
#pragma unroll
  for (int m = 1; m < 64; m <<= 1) a += __shfl_xor(a, m, 64);
  __shared__ float red[4];
  if ((tid & 63) == 0) red[tid >> 6] = a;
  __syncthreads();
  if (tid == 0) out[0] = (red[0] + red[1] + red[2] + red[3]) * (1.0f / N_ROWS);
}

extern "C" void kernel_launch(void* const* d_in, const int* in_sizes, int n_in,
                              void* d_out, int out_size, void* d_ws, size_t ws_size,
                              hipStream_t stream) {
  const float* f1 = (const float*)d_in[0];
  const float* f2 = (const float*)d_in[1];
  unsigned short* F = (unsigned short*)d_ws;                         // 16 MiB bf16 normalized features
  float* rowsum = (float*)((char*)d_ws + (size_t)N_ROWS * D_DIM * 2); // 32 KiB
  float* pos    = rowsum + N_ROWS;                                    // 32 KiB
  float* out    = (float*)d_out;

  hipLaunchKernelGGL(normalize_kernel, dim3(N_ROWS), dim3(256), 0, stream, f1, f2, F, rowsum);
  hipLaunchKernelGGL(simloss_kernel, dim3(64, 64), dim3(256), 0, stream, F, rowsum, pos);
  hipLaunchKernelGGL(finalize_kernel, dim3(1), dim3(256), 0, stream, rowsum, pos, out);
}

// Round 2
// 210.746 us; speedup vs baseline: 1.5020x; 1.5020x over previous
//
#include <hip/hip_runtime.h>
#include <stdint.h>

#define B_ROWS 4096
#define N_ROWS 8192
#define D_DIM  1024
#define BK     64
#define NBLK   64   // 8192 / 128 tile blocks per dim

typedef __attribute__((ext_vector_type(8))) short bf16x8;
typedef __attribute__((ext_vector_type(4))) float f32x4;

// round-to-nearest-even f32 -> bf16
static __device__ __forceinline__ unsigned short f2bf(float f) {
  uint32_t u = __float_as_uint(f);
  u += 0x7fff + ((u >> 16) & 1);
  return (unsigned short)(u >> 16);
}

static __device__ __forceinline__ void async_copy16(const unsigned short* g, unsigned short* l) {
  __builtin_amdgcn_global_load_lds(
      (const __attribute__((address_space(1))) unsigned int*)g,
      (__attribute__((address_space(3))) unsigned int*)l, 16, 0, 0);
}

// One block per row: L2-normalize, cast to bf16, and zero rowsum.
__global__ __launch_bounds__(256) void normalize_kernel(
    const float* __restrict__ f1, const float* __restrict__ f2,
    unsigned short* __restrict__ F, float* __restrict__ rowsum) {
  const int row = blockIdx.x;
  const int tid = threadIdx.x;
  const float* src = (row < B_ROWS) ? (f1 + (size_t)row * D_DIM)
                                    : (f2 + (size_t)(row - B_ROWS) * D_DIM);
  float4 v = ((const float4*)src)[tid];
  float ss = v.x * v.x + v.y * v.y + v.z * v.z + v.w * v.w;
#pragma unroll
  for (int m = 1; m < 64; m <<= 1) ss += __shfl_xor(ss, m, 64);
  __shared__ float red[4];
  if ((tid & 63) == 0) red[tid >> 6] = ss;
  __syncthreads();
  ss = red[0] + red[1] + red[2] + red[3];
  const float invn = 1.0f / fmaxf(sqrtf(ss), 1e-12f);
  ushort4 o;
  o.x = f2bf(v.x * invn); o.y = f2bf(v.y * invn);
  o.z = f2bf(v.z * invn); o.w = f2bf(v.w * invn);
  ((ushort4*)(F + (size_t)row * D_DIM))[tid] = o;
  if (tid == 0) rowsum[row] = 0.0f;
}

// Fused Gram-GEMM + exp-sum epilogue over UPPER-TRIANGULAR block grid only
// (sim is symmetric: off-diag tiles feed rowsum[i] via row-reduce and
// rowsum[j] via column-reduce). 128x128 tile / block, 4 waves,
// each wave 64x64 via 4x4 grid of 16x16x32 bf16 MFMA.
__global__ __launch_bounds__(256) void simloss_kernel(
    const unsigned short* __restrict__ F, float* __restrict__ rowsum,
    float* __restrict__ pos) {
  __shared__ unsigned short lA[128 * BK];
  __shared__ unsigned short lB[128 * BK];

  // decode linear block id -> (bi, bj), bi <= bj (upper triangle)
  int rem = blockIdx.x;
  int bi = 0;
  while (rem >= NBLK - bi) { rem -= NBLK - bi; ++bi; }
  const int bj = bi + rem;

  const int tid  = threadIdx.x;
  const int lane = tid & 63;
  const int wv   = __builtin_amdgcn_readfirstlane(tid >> 6);
  const int waveRow = wv >> 1;
  const int waveCol = wv & 1;
  const int q   = lane >> 4;   // quad within wave
  const int l16 = lane & 15;

  const int iBase = bi * 128;
  const int jBase = bj * 128;

  f32x4 acc[4][4];
#pragma unroll
  for (int a = 0; a < 4; ++a)
#pragma unroll
    for (int b = 0; b < 4; ++b) acc[a][b] = (f32x4){0.f, 0.f, 0.f, 0.f};

  for (int k0 = 0; k0 < D_DIM; k0 += BK) {
    // ---- stage A (rows i) and B (rows j) tiles, XOR-swizzled chunks ----
    // LDS chunk lc (16B) holds global [row = lc>>3][col8 = (lc&7) ^ (row&7)]
#pragma unroll
    for (int it = 0; it < 4; ++it) {
      const int lc   = it * 256 + wv * 64 + lane;
      const int row  = lc >> 3;
      const int gcol = (lc & 7) ^ (row & 7);
      const size_t goff = (size_t)row * D_DIM + k0 + gcol * 8;
      async_copy16(F + (size_t)iBase * D_DIM + goff, lA + lc * 8);
      async_copy16(F + (size_t)jBase * D_DIM + goff, lB + lc * 8);
    }
    __syncthreads();

    // ---- compute: 2 k-substeps of 32 ----
#pragma unroll
    for (int kk = 0; kk < BK; kk += 32) {
      bf16x8 af[4], bfr[4];
      const int cbase = (kk >> 3) + q;
#pragma unroll
      for (int mi = 0; mi < 4; ++mi) {
        const int r  = waveRow * 64 + mi * 16 + l16;
        const int ch = r * 8 + (cbase ^ (r & 7));
        af[mi] = *(const bf16x8*)(lA + ch * 8);
      }
#pragma unroll
      for (int ni = 0; ni < 4; ++ni) {
        const int r  = waveCol * 64 + ni * 16 + l16;
        const int ch = r * 8 + (cbase ^ (r & 7));
        bfr[ni] = *(const bf16x8*)(lB + ch * 8);
      }
#pragma unroll
      for (int mi = 0; mi < 4; ++mi)
#pragma unroll
        for (int ni = 0; ni < 4; ++ni)
          acc[mi][ni] = __builtin_amdgcn_mfma_f32_16x16x32_bf16(
              af[mi], bfr[ni], acc[mi][ni], 0, 0, 0);
    }
    __syncthreads();
  }

  // ---- epilogue ----
  // sim = 10*dot; e = exp(sim-10) excluding diagonal.
  // Row-reduce -> rowsum[i]; for off-diag tiles also column-reduce -> rowsum[j].
  const bool offdiag = (bi != bj);
  float colAcc[4] = {0.f, 0.f, 0.f, 0.f};  // per-ni, this lane's column partial

#pragma unroll
  for (int mi = 0; mi < 4; ++mi) {
#pragma unroll
    for (int reg = 0; reg < 4; ++reg) {
      const int i = iBase + waveRow * 64 + mi * 16 + q * 4 + reg;
      float s = 0.0f;
#pragma unroll
      for (int ni = 0; ni < 4; ++ni) {
        const int j = jBase + waveCol * 64 + ni * 16 + l16;
        const float sim = acc[mi][ni][reg] * 10.0f;
        const float e = (j == i) ? 0.0f : __expf(sim - 10.0f);
        s += e;
        colAcc[ni] += e;
        if (i < B_ROWS && j == i + B_ROWS) pos[i] = sim;
      }
      // reduce across the 16 lanes (same q, varying l16) sharing row i
#pragma unroll
      for (int m = 1; m < 16; m <<= 1) s += __shfl_xor(s, m, 64);
      if (l16 == 0) atomicAdd(&rowsum[i], s);
    }
  }

  if (offdiag) {
    // column sums: reduce across quads (lanes sharing l16), then q==0 lanes
    // hold the per-column total for j = jBase + waveCol*64 + ni*16 + l16
#pragma unroll
    for (int ni = 0; ni < 4; ++ni) {
      float c = colAcc[ni];
#pragma unroll
      for (int m = 16; m < 64; m <<= 1) c += __shfl_xor(c, m, 64);
      if (q == 0) {
        const int j = jBase + waveCol * 64 + ni * 16 + l16;
        atomicAdd(&rowsum[j], c);
      }
    }
  }
}

__global__ __launch_bounds__(1024) void finalize_kernel(
    const float* __restrict__ rowsum, const float* __restrict__ pos,
    float* __restrict__ out) {
  const int tid = threadIdx.x;
  float a = 0.0f;
  for (int i = tid; i < N_ROWS; i += 1024)
    a += logf(rowsum[i]) + 10.0f - pos[i & (B_ROWS - 1)];
#pragma unroll
  for (int m = 1; m < 64; m <<= 1) a += __shfl_xor(a, m, 64);
  __shared__ float red[16];
  if ((tid & 63) == 0) red[tid >> 6] = a;
  __syncthreads();
  if (tid == 0) {
    float t = 0.0f;
#pragma unroll
    for (int w = 0; w < 16; ++w) t += red[w];
    out[0] = t * (1.0f / N_ROWS);
  }
}

extern "C" void kernel_launch(void* const* d_in, const int* in_sizes, int n_in,
                              void* d_out, int out_size, void* d_ws, size_t ws_size,
                              hipStream_t stream) {
  const float* f1 = (const float*)d_in[0];
  const float* f2 = (const float*)d_in[1];
  unsigned short* F = (unsigned short*)d_ws;                          // 16 MiB bf16 normalized features
  float* rowsum = (float*)((char*)d_ws + (size_t)N_ROWS * D_DIM * 2); // 32 KiB
  float* pos    = rowsum + N_ROWS;                                    // 16 KiB used (i < B_ROWS)
  float* out    = (float*)d_out;

  const int nTri = NBLK * (NBLK + 1) / 2;  // 2080 upper-triangular tiles
  hipLaunchKernelGGL(normalize_kernel, dim3(N_ROWS), dim3(256), 0, stream, f1, f2, F, rowsum);
  hipLaunchKernelGGL(simloss_kernel, dim3(nTri), dim3(256), 0, stream, F, rowsum, pos);
  hipLaunchKernelGGL(finalize_kernel, dim3(1), dim3(1024), 0, stream, rowsum, pos, out);
}